// Round 6
// baseline (39025.336 us; speedup 1.0000x reference)
//
#include <hip/hip_runtime.h>
#include <stdint.h>

typedef unsigned short u16;
typedef __attribute__((ext_vector_type(8))) short bf16x8;
typedef __attribute__((ext_vector_type(4))) float f32x4;
typedef __attribute__((ext_vector_type(4))) u16 u16x4;

#define NBLK 240

__device__ __forceinline__ u16 f2bf(float f) {
  union { float f; uint32_t u; } v; v.f = f;
  uint32_t u = v.u;
  uint32_t r = u + 0x7fffu + ((u >> 16) & 1u);
  return (u16)(r >> 16);
}
__device__ __forceinline__ float bf2f(u16 h) {
  union { uint32_t u; float f; } v; v.u = ((uint32_t)h) << 16; return v.f;
}
__device__ __forceinline__ float sigm(float x) { return 1.f / (1.f + __expf(-x)); }
__device__ __forceinline__ float tanhfast(float x) {
  float t = __expf(-2.f * fabsf(x));
  float r = (1.f - t) / (1.f + t);
  return x < 0.f ? -r : r;
}

// grid barrier: monotone counter, agent-scope release/acquire
__device__ __forceinline__ void gbar(unsigned* cnt, unsigned target) {
  __syncthreads();
  if (threadIdx.x == 0) {
    __threadfence();   // release: make this block's writes device-visible
    __hip_atomic_fetch_add(cnt, 1u, __ATOMIC_RELEASE, __HIP_MEMORY_SCOPE_AGENT);
    while (__hip_atomic_load(cnt, __ATOMIC_ACQUIRE, __HIP_MEMORY_SCOPE_AGENT) <
           target) {
      __builtin_amdgcn_s_sleep(8);
    }
    __threadfence();   // acquire: invalidate stale cache
  }
  __syncthreads();
}

__global__ __launch_bounds__(256) void k_zero(float* __restrict__ p, int n) {
  int i = blockIdx.x * 256 + threadIdx.x;
  if (i < n) p[i] = 0.f;
}

// Repack Wih||Whh (fp32) -> bf16 fragment-tiled: [l][jb(120)][k0(120)][g(4)][lane(64)][8]
// total threads = 2*120*120*4*64 = 7,372,800  -> grid 28800 x 256
__global__ __launch_bounds__(256) void k_repB(const float* __restrict__ Wih,
                                              const float* __restrict__ Whh,
                                              u16* __restrict__ dst) {
  int e8 = blockIdx.x * 256 + threadIdx.x;
  if (e8 >= 7372800) return;
  int lane = e8 & 63;
  int t1 = e8 >> 6;
  int g = t1 & 3;
  int t2 = t1 >> 2;
  int k0 = t2 % 120;
  int t3 = t2 / 120;
  int jb = t3 % 120;
  int l = t3 / 120;
  int ln = lane & 15, quad = lane >> 4;
  int n = g * 1920 + jb * 16 + ln;
  const float* src = (k0 < 60)
      ? (Wih + ((size_t)(l * 7680 + n)) * 1920 + k0 * 32 + quad * 8)
      : (Whh + ((size_t)(l * 7680 + n)) * 1920 + (k0 - 60) * 32 + quad * 8);
  float4 a = ((const float4*)src)[0];
  float4 b = ((const float4*)src)[1];
  u16x4 o0, o1;
  o0[0] = f2bf(a.x); o0[1] = f2bf(a.y); o0[2] = f2bf(a.z); o0[3] = f2bf(a.w);
  o1[0] = f2bf(b.x); o1[1] = f2bf(b.y); o1[2] = f2bf(b.z); o1[3] = f2bf(b.w);
  ((u16x4*)(dst + (size_t)e8 * 8))[0] = o0;
  ((u16x4*)(dst + (size_t)e8 * 8))[1] = o1;
}

// Repack W3 (fp32 [1920,1920]) -> [nb(30)][k0(60)][nt(4)][lane(64)][8]
// total threads = 30*60*4*64 = 460,800 -> grid 1800 x 256
__global__ __launch_bounds__(256) void k_repW3(const float* __restrict__ W3,
                                               u16* __restrict__ dst) {
  int e8 = blockIdx.x * 256 + threadIdx.x;
  if (e8 >= 460800) return;
  int lane = e8 & 63;
  int t1 = e8 >> 6;
  int nt = t1 & 3;
  int t2 = t1 >> 2;
  int k0 = t2 % 60;
  int nb = t2 / 60;
  int ln = lane & 15, quad = lane >> 4;
  int n = nb * 64 + nt * 16 + ln;
  const float* src = W3 + (size_t)n * 1920 + k0 * 32 + quad * 8;
  float4 a = ((const float4*)src)[0];
  float4 b = ((const float4*)src)[1];
  u16x4 o0, o1;
  o0[0] = f2bf(a.x); o0[1] = f2bf(a.y); o0[2] = f2bf(a.z); o0[3] = f2bf(a.w);
  o1[0] = f2bf(b.x); o1[1] = f2bf(b.y); o1[2] = f2bf(b.z); o1[3] = f2bf(b.w);
  ((u16x4*)(dst + (size_t)e8 * 8))[0] = o0;
  ((u16x4*)(dst + (size_t)e8 * 8))[1] = o1;
}

struct P {
  const float* inputs;
  const float* W1; const float* b1; const float* W2; const float* b2;
  const float* bih; const float* bhh;
  const float* b3; const float* W4; const float* b4;
  const int* burn;
  float* outp;
  float* cbuf;
  u16* A0; u16* A1; u16* A2; u16* X3b;
  const u16* Brep; const u16* W3r;
  unsigned* bar;
};

// Rolling-pipeline fragment GEMM: ITERS k-iters (32 k each), depth 5.
// Requires (ITERS-5) % 5 == 0.
template <int ITERS>
__device__ __forceinline__ void gemm_pipe(const char* __restrict__ aw,
                                          const char* __restrict__ bw,
                                          int lane_off, f32x4 acc[4][4]) {
  constexpr int D = 5;
  bf16x8 Af[D][4], Bf[D][4];
#pragma unroll
  for (int p = 0; p < D; ++p) {
#pragma unroll
    for (int mt = 0; mt < 4; ++mt)
      Af[p][mt] = *(const bf16x8*)(aw + p * 4096 + mt * 1024 + lane_off);
#pragma unroll
    for (int nt = 0; nt < 4; ++nt)
      Bf[p][nt] = *(const bf16x8*)(bw + p * 4096 + nt * 1024 + lane_off);
  }
  for (int o = 0; o < (ITERS - D) / D; ++o) {
    const char* ap = aw + (size_t)(o + 1) * (D * 4096);
    const char* bp = bw + (size_t)(o + 1) * (D * 4096);
#pragma unroll
    for (int d = 0; d < D; ++d) {
#pragma unroll
      for (int mt = 0; mt < 4; ++mt)
#pragma unroll
        for (int nt = 0; nt < 4; ++nt)
          acc[mt][nt] = __builtin_amdgcn_mfma_f32_16x16x32_bf16(
              Af[d][mt], Bf[d][nt], acc[mt][nt], 0, 0, 0);
#pragma unroll
      for (int mt = 0; mt < 4; ++mt)
        Af[d][mt] = *(const bf16x8*)(ap + d * 4096 + mt * 1024 + lane_off);
#pragma unroll
      for (int nt = 0; nt < 4; ++nt)
        Bf[d][nt] = *(const bf16x8*)(bp + d * 4096 + nt * 1024 + lane_off);
    }
  }
#pragma unroll
  for (int d = 0; d < D; ++d) {
#pragma unroll
    for (int mt = 0; mt < 4; ++mt)
#pragma unroll
      for (int nt = 0; nt < 4; ++nt)
        acc[mt][nt] = __builtin_amdgcn_mfma_f32_16x16x32_bf16(
            Af[d][mt], Bf[d][nt], acc[mt][nt], 0, 0, 0);
  }
}

// per-atom MLP (all 64 lanes of one wave; ins uniform across lanes)
__device__ __forceinline__ void mlp_core(const P& p, int b, int a, int lane,
                                         const float ins[4]) {
  int j = lane;
  float h1 = p.b1[j] + ins[0] * p.W1[j * 4 + 0] + ins[1] * p.W1[j * 4 + 1] +
             ins[2] * p.W1[j * 4 + 2] + ins[3] * p.W1[j * 4 + 3];
  h1 = fmaxf(h1, 0.f);
  float h2 = p.b2[j];
  const float4* w2r = (const float4*)(p.W2 + j * 64);
#pragma unroll
  for (int k4 = 0; k4 < 16; ++k4) {
    float4 wv = w2r[k4];
    h2 += __shfl(h1, k4 * 4 + 0) * wv.x + __shfl(h1, k4 * 4 + 1) * wv.y +
          __shfl(h1, k4 * 4 + 2) * wv.z + __shfl(h1, k4 * 4 + 3) * wv.w;
  }
  h2 = fmaxf(h2, 0.f);
  int mh = b >> 6, mloc = b & 63, mt = mloc >> 4, ln2 = mloc & 15;
  int ch = a * 2 + (j >> 5), quad2 = (j >> 3) & 3, jj = j & 7;
  size_t xi = ((size_t)(mh * 180 + ch) * 4 + mt) * 512 + (quad2 * 16 + ln2) * 8 + jj;
  p.A0[xi] = f2bf(h2);
}

// Gates GEMM + fused LSTM cell: block = (jb, mh); wave w = K-chunk w (30 iters);
// LDS reduce; wave w applies the cell to m-tile w. nt == gate (i,f,g,o).
__device__ __forceinline__ void gates_unit(const P& p, int layer, int jb, int mh,
                                           int w, int lane,
                                           float (&red)[4][4][16][64],
                                           int rd_off, int wr_off) {
  const int ln = lane & 15, quad = lane >> 4;
  const int lane_off = lane * 16;
  const u16* Atl = layer ? p.A1 : p.A0;
  const char* ax = (const char*)Atl + (size_t)mh * 180 * 4096;
  const char* ah = ax + (size_t)rd_off * 4096;
  const char* aw = (w < 2) ? (ax + (size_t)(30 * w) * 4096)
                           : (ah + (size_t)(30 * (w - 2)) * 4096);
  const char* bw = (const char*)(p.Brep + (size_t)layer * 120 * 120 * 2048) +
                   ((size_t)jb * 120 + 30 * w) * 4096;
  const float* bihl = p.bih + layer * 7680;
  const float* bhhl = p.bhh + layer * 7680;
  float* c_l = p.cbuf + layer * 245760;
  u16* hA = (layer ? p.A1 : p.A0) + (size_t)wr_off * 2048;
  u16* hB = layer ? p.A2 : p.A1;
  const int sB = layer ? 60 : 180;

  f32x4 acc[4][4] = {};
  gemm_pipe<30>(aw, bw, lane_off, acc);

#pragma unroll
  for (int mt = 0; mt < 4; ++mt)
#pragma unroll
    for (int nt = 0; nt < 4; ++nt)
      *(f32x4*)&red[w][nt][ln][mt * 16 + quad * 4] = acc[mt][nt];
  __syncthreads();

  f32x4 g[4];
#pragma unroll
  for (int nt = 0; nt < 4; ++nt) {
    f32x4 s = *(const f32x4*)&red[0][nt][ln][w * 16 + quad * 4];
#pragma unroll
    for (int pp = 1; pp < 4; ++pp) {
      f32x4 tv = *(const f32x4*)&red[pp][nt][ln][w * 16 + quad * 4];
      s[0] += tv[0]; s[1] += tv[1]; s[2] += tv[2]; s[3] += tv[3];
    }
    g[nt] = s;
  }

  const int kh = jb * 16 + ln;
  const int chl = kh >> 5, quad2 = (kh >> 3) & 3, jj = kh & 7;
  float bs[4];
#pragma unroll
  for (int gi = 0; gi < 4; ++gi) bs[gi] = bihl[gi * 1920 + kh] + bhhl[gi * 1920 + kh];
#pragma unroll
  for (int r = 0; r < 4; ++r) {
    int m = mh * 64 + w * 16 + quad * 4 + r;
    float vi = g[0][r] + bs[0];
    float vf = g[1][r] + bs[1];
    float vg = g[2][r] + bs[2];
    float vo = g[3][r] + bs[3];
    size_t ci = (size_t)m * 1920 + kh;
    float cn = sigm(vf) * c_l[ci] + sigm(vi) * tanhfast(vg);
    float hn = sigm(vo) * tanhfast(cn);
    c_l[ci] = cn;
    u16 hb = f2bf(hn);
    int lane2 = quad2 * 16 + quad * 4 + r;
    size_t hi = ((size_t)(mh * 180 + chl) * 4 + w) * 512 + lane2 * 8 + jj;
    hA[hi] = hb;
    size_t hi2 = ((size_t)(mh * sB + chl) * 4 + w) * 512 + lane2 * 8 + jj;
    hB[hi2] = hb;
  }
}

// W3 GEMM + relu -> plain bf16 [128,1920]. block = (nb, mh), 4-wave K-split.
__device__ __forceinline__ void w3_unit(const P& p, int nb, int mh, int w, int lane,
                                        float (&red)[4][4][16][64]) {
  const int ln = lane & 15, quad = lane >> 4;
  const int lane_off = lane * 16;
  const char* aw = (const char*)p.A2 + ((size_t)mh * 60 + 15 * w) * 4096;
  const char* bw = (const char*)p.W3r + ((size_t)nb * 60 + 15 * w) * 4096;

  f32x4 acc[4][4] = {};
  gemm_pipe<15>(aw, bw, lane_off, acc);

#pragma unroll
  for (int mt = 0; mt < 4; ++mt)
#pragma unroll
    for (int nt = 0; nt < 4; ++nt)
      *(f32x4*)&red[w][nt][ln][mt * 16 + quad * 4] = acc[mt][nt];
  __syncthreads();

#pragma unroll
  for (int nt = 0; nt < 4; ++nt) {
    f32x4 s = *(const f32x4*)&red[0][nt][ln][w * 16 + quad * 4];
#pragma unroll
    for (int pp = 1; pp < 4; ++pp) {
      f32x4 tv = *(const f32x4*)&red[pp][nt][ln][w * 16 + quad * 4];
      s[0] += tv[0]; s[1] += tv[1]; s[2] += tv[2]; s[3] += tv[3];
    }
    int n = nb * 64 + nt * 16 + ln;
    float bias = p.b3[n];
#pragma unroll
    for (int r = 0; r < 4; ++r) {
      int m = mh * 64 + w * 16 + quad * 4 + r;
      p.X3b[(size_t)m * 1920 + n] = f2bf(fmaxf(s[r] + bias, 0.f));
    }
  }
}

// W4 projection + bias + residual for unit (m,pb); then (fused) next-step MLP for
// atoms 2pb, 2pb+1 — ins values stay in registers across timesteps.
__device__ __forceinline__ void w4mlp_unit(const P& p, int m, int pb, int lane,
                                           int t, float* insreg, bool do_mlp,
                                           int burn) {
  const u16* xr = p.X3b + (size_t)m * 1920;
  float xv[30];
#pragma unroll
  for (int i = 0; i < 30; ++i) xv[i] = bf2f(xr[lane + 64 * i]);
  float vs[8];
#pragma unroll
  for (int pi = 0; pi < 8; ++pi) {
    int pp = pb * 8 + pi;
    const float* wr = p.W4 + (size_t)pp * 1920;
    float s = 0.f;
#pragma unroll
    for (int i = 0; i < 30; ++i) s += xv[i] * wr[lane + 64 * i];
#pragma unroll
    for (int off = 32; off > 0; off >>= 1) s += __shfl_xor(s, off);
    float v = s + p.b4[pp] + insreg[pi];
    vs[pi] = v;
    if (lane == 0)
      p.outp[(((size_t)m * 30 + (pp >> 2)) * 64 + t) * 4 + (pp & 3)] = v;
  }
  if (do_mlp) {
    bool gt = (t + 1) <= burn;
#pragma unroll
    for (int ai = 0; ai < 2; ++ai) {
      int a = pb * 2 + ai;
      int ba = m * 30 + a;
      float ins[4];
#pragma unroll
      for (int f = 0; f < 4; ++f)
        ins[f] = gt ? p.inputs[((size_t)ba * 65 + (t + 1)) * 4 + f] : vs[ai * 4 + f];
      mlp_core(p, m, a, lane, ins);
#pragma unroll
      for (int f = 0; f < 4; ++f) insreg[ai * 4 + f] = ins[f];
    }
  }
}

__global__ void __launch_bounds__(256, 1) k_persist(P p) {
  __shared__ float red[4][4][16][64];   // 64 KB
  const int bid = blockIdx.x;
  const int tid = threadIdx.x;
  const int w = tid >> 6, lane = tid & 63;
  const int burn = *p.burn;
  unsigned nbar = 0;

  // static unit assignment for w4+mlp: two (m,pb) units per wave
  int um[2], upb[2];
  float insreg[2][8];
#pragma unroll
  for (int u2 = 0; u2 < 2; ++u2) {
    int u = bid * 8 + w * 2 + u2;
    um[u2] = u / 15;
    upb[u2] = u - um[u2] * 15;
  }

  // t=0 MLP phase (ground-truth inputs; t=0 <= burn always)
#pragma unroll
  for (int u2 = 0; u2 < 2; ++u2) {
    int m = um[u2], pb = upb[u2];
#pragma unroll
    for (int ai = 0; ai < 2; ++ai) {
      int a = pb * 2 + ai, ba = m * 30 + a;
      float ins[4];
#pragma unroll
      for (int f = 0; f < 4; ++f)
        ins[f] = p.inputs[((size_t)ba * 65 + 0) * 4 + f];
      mlp_core(p, m, a, lane, ins);
#pragma unroll
      for (int f = 0; f < 4; ++f) insreg[u2][ai * 4 + f] = ins[f];
    }
  }
  nbar++; gbar(p.bar, nbar * NBLK);

  for (int t = 0; t < 64; ++t) {
    const int par = t & 1;
    const int rd_off = 60 + par * 60;
    const int wr_off = 60 + (1 - par) * 60;

    gates_unit(p, 0, bid >> 1, bid & 1, w, lane, red, rd_off, wr_off);
    nbar++; gbar(p.bar, nbar * NBLK);
    gates_unit(p, 1, bid >> 1, bid & 1, w, lane, red, rd_off, wr_off);
    nbar++; gbar(p.bar, nbar * NBLK);
    if (bid < 60) w3_unit(p, bid >> 1, bid & 1, w, lane, red);
    nbar++; gbar(p.bar, nbar * NBLK);
    const bool do_mlp = (t < 63);
#pragma unroll
    for (int u2 = 0; u2 < 2; ++u2)
      w4mlp_unit(p, um[u2], upb[u2], lane, t, insreg[u2], do_mlp, burn);
    nbar++; gbar(p.bar, nbar * NBLK);
  }
}

extern "C" void kernel_launch(void* const* d_in, const int* in_sizes, int n_in,
                              void* d_out, int out_size, void* d_ws, size_t ws_size,
                              hipStream_t stream) {
  (void)in_sizes; (void)n_in; (void)out_size;
  const float* inputs = (const float*)d_in[0];
  const float* W1 = (const float*)d_in[1];
  const float* b1 = (const float*)d_in[2];
  const float* W2 = (const float*)d_in[3];
  const float* b2 = (const float*)d_in[4];
  const float* Wih = (const float*)d_in[5];
  const float* Whh = (const float*)d_in[6];
  const float* bih = (const float*)d_in[7];
  const float* bhh = (const float*)d_in[8];
  const float* W3 = (const float*)d_in[9];
  const float* b3 = (const float*)d_in[10];
  const float* W4 = (const float*)d_in[11];
  const float* b4 = (const float*)d_in[12];
  const int* burn = (const int*)d_in[14];
  float* outp = (float*)d_out;
  char* ws = (char*)d_ws;

  // ---- workspace layout (bytes) ----
  // zero region: c (1966080) + A0 (1474560) + A1 (1474560) + bar (256) = 4915456
  float* cbuf = (float*)ws;                          // [2][128][1920] f32
  u16* A0 = (u16*)(ws + 1966080);                    // [2mh][180ch][4][512] u16
  u16* A1 = (u16*)(ws + 3440640);
  unsigned* bar = (unsigned*)(ws + 4915200);         // barrier counter (zeroed)
  u16* A2 = (u16*)(ws + 4915456);                    // [2mh][60ch][4][512] u16
  u16* X3b = (u16*)(ws + 5406976);                   // [128][1920] bf16
  u16* Brep = (u16*)(ws + 5898496);                  // 58982400 u16
  u16* W3r = (u16*)(ws + 123863296);                 // 3686400 u16
  if (ws_size < 131236096) return;                   // insufficient scratch

  // zero c + A0 + A1 + bar (1228864 floats)
  hipLaunchKernelGGL(k_zero, dim3(4801), dim3(256), 0, stream, (float*)ws,
                     1228864);
  // repack weights to bf16 fragment-tiled
  hipLaunchKernelGGL(k_repB, dim3(28800), dim3(256), 0, stream, Wih, Whh, Brep);
  hipLaunchKernelGGL(k_repW3, dim3(1800), dim3(256), 0, stream, W3, W3r);

  P prm;
  prm.inputs = inputs;
  prm.W1 = W1; prm.b1 = b1; prm.W2 = W2; prm.b2 = b2;
  prm.bih = bih; prm.bhh = bhh;
  prm.b3 = b3; prm.W4 = W4; prm.b4 = b4;
  prm.burn = burn;
  prm.outp = outp;
  prm.cbuf = cbuf;
  prm.A0 = A0; prm.A1 = A1; prm.A2 = A2; prm.X3b = X3b;
  prm.Brep = Brep; prm.W3r = W3r;
  prm.bar = bar;

  hipLaunchKernelGGL(k_persist, dim3(NBLK), dim3(256), 0, stream, prm);
}

// Round 7
// 28390.436 us; speedup vs baseline: 1.3746x; 1.3746x over previous
//
#include <hip/hip_runtime.h>
#include <stdint.h>

typedef unsigned short u16;
typedef __attribute__((ext_vector_type(8))) short bf16x8;
typedef __attribute__((ext_vector_type(4))) float f32x4;
typedef __attribute__((ext_vector_type(4))) u16 u16x4;

#define NBLK 240

__device__ __forceinline__ u16 f2bf(float f) {
  union { float f; uint32_t u; } v; v.f = f;
  uint32_t u = v.u;
  uint32_t r = u + 0x7fffu + ((u >> 16) & 1u);
  return (u16)(r >> 16);
}
__device__ __forceinline__ float bf2f(u16 h) {
  union { uint32_t u; float f; } v; v.u = ((uint32_t)h) << 16; return v.f;
}
__device__ __forceinline__ float sigm(float x) { return 1.f / (1.f + __expf(-x)); }
__device__ __forceinline__ float tanhfast(float x) {
  float t = __expf(-2.f * fabsf(x));
  float r = (1.f - t) / (1.f + t);
  return x < 0.f ? -r : r;
}

// grid barrier: release-fence + relaxed add; RELAXED poll (no per-poll L2
// invalidate!); single acquire-fence after target observed.
__device__ __forceinline__ void gbar(unsigned* cnt, unsigned target) {
  __syncthreads();
  if (threadIdx.x == 0) {
    __builtin_amdgcn_fence(__ATOMIC_RELEASE, "agent");   // L2 writeback
    __hip_atomic_fetch_add(cnt, 1u, __ATOMIC_RELAXED, __HIP_MEMORY_SCOPE_AGENT);
    while (__hip_atomic_load(cnt, __ATOMIC_RELAXED, __HIP_MEMORY_SCOPE_AGENT) <
           target) {
      __builtin_amdgcn_s_sleep(2);
    }
    __builtin_amdgcn_fence(__ATOMIC_ACQUIRE, "agent");   // one L2 invalidate
  }
  __syncthreads();
}

__global__ __launch_bounds__(256) void k_zero(float* __restrict__ p, int n) {
  int i = blockIdx.x * 256 + threadIdx.x;
  if (i < n) p[i] = 0.f;
}

// Repack Wih||Whh (fp32) -> bf16 fragment-tiled: [l][jb(120)][k0(120)][g(4)][lane(64)][8]
// total threads = 2*120*120*4*64 = 7,372,800  -> grid 28800 x 256
__global__ __launch_bounds__(256) void k_repB(const float* __restrict__ Wih,
                                              const float* __restrict__ Whh,
                                              u16* __restrict__ dst) {
  int e8 = blockIdx.x * 256 + threadIdx.x;
  if (e8 >= 7372800) return;
  int lane = e8 & 63;
  int t1 = e8 >> 6;
  int g = t1 & 3;
  int t2 = t1 >> 2;
  int k0 = t2 % 120;
  int t3 = t2 / 120;
  int jb = t3 % 120;
  int l = t3 / 120;
  int ln = lane & 15, quad = lane >> 4;
  int n = g * 1920 + jb * 16 + ln;
  const float* src = (k0 < 60)
      ? (Wih + ((size_t)(l * 7680 + n)) * 1920 + k0 * 32 + quad * 8)
      : (Whh + ((size_t)(l * 7680 + n)) * 1920 + (k0 - 60) * 32 + quad * 8);
  float4 a = ((const float4*)src)[0];
  float4 b = ((const float4*)src)[1];
  u16x4 o0, o1;
  o0[0] = f2bf(a.x); o0[1] = f2bf(a.y); o0[2] = f2bf(a.z); o0[3] = f2bf(a.w);
  o1[0] = f2bf(b.x); o1[1] = f2bf(b.y); o1[2] = f2bf(b.z); o1[3] = f2bf(b.w);
  ((u16x4*)(dst + (size_t)e8 * 8))[0] = o0;
  ((u16x4*)(dst + (size_t)e8 * 8))[1] = o1;
}

// Repack W3 (fp32 [1920,1920]) -> [nb(30)][k0(60)][nt(4)][lane(64)][8]
// total threads = 30*60*4*64 = 460,800 -> grid 1800 x 256
__global__ __launch_bounds__(256) void k_repW3(const float* __restrict__ W3,
                                               u16* __restrict__ dst) {
  int e8 = blockIdx.x * 256 + threadIdx.x;
  if (e8 >= 460800) return;
  int lane = e8 & 63;
  int t1 = e8 >> 6;
  int nt = t1 & 3;
  int t2 = t1 >> 2;
  int k0 = t2 % 60;
  int nb = t2 / 60;
  int ln = lane & 15, quad = lane >> 4;
  int n = nb * 64 + nt * 16 + ln;
  const float* src = W3 + (size_t)n * 1920 + k0 * 32 + quad * 8;
  float4 a = ((const float4*)src)[0];
  float4 b = ((const float4*)src)[1];
  u16x4 o0, o1;
  o0[0] = f2bf(a.x); o0[1] = f2bf(a.y); o0[2] = f2bf(a.z); o0[3] = f2bf(a.w);
  o1[0] = f2bf(b.x); o1[1] = f2bf(b.y); o1[2] = f2bf(b.z); o1[3] = f2bf(b.w);
  ((u16x4*)(dst + (size_t)e8 * 8))[0] = o0;
  ((u16x4*)(dst + (size_t)e8 * 8))[1] = o1;
}

struct P {
  const float* inputs;
  const float* W1; const float* b1; const float* W2; const float* b2;
  const float* bih; const float* bhh;
  const float* b3; const float* W4; const float* b4;
  const int* burn;
  float* outp;
  float* cbuf;
  u16* A0; u16* A1; u16* A2; u16* X3b;
  const u16* Brep; const u16* W3r;
  unsigned* bar;
};

// Rolling-pipeline fragment GEMM: ITERS k-iters (32 k each), depth 5.
// Requires (ITERS-5) % 5 == 0.
template <int ITERS>
__device__ __forceinline__ void gemm_pipe(const char* __restrict__ aw,
                                          const char* __restrict__ bw,
                                          int lane_off, f32x4 acc[4][4]) {
  constexpr int D = 5;
  bf16x8 Af[D][4], Bf[D][4];
#pragma unroll
  for (int p = 0; p < D; ++p) {
#pragma unroll
    for (int mt = 0; mt < 4; ++mt)
      Af[p][mt] = *(const bf16x8*)(aw + p * 4096 + mt * 1024 + lane_off);
#pragma unroll
    for (int nt = 0; nt < 4; ++nt)
      Bf[p][nt] = *(const bf16x8*)(bw + p * 4096 + nt * 1024 + lane_off);
  }
  for (int o = 0; o < (ITERS - D) / D; ++o) {
    const char* ap = aw + (size_t)(o + 1) * (D * 4096);
    const char* bp = bw + (size_t)(o + 1) * (D * 4096);
#pragma unroll
    for (int d = 0; d < D; ++d) {
#pragma unroll
      for (int mt = 0; mt < 4; ++mt)
#pragma unroll
        for (int nt = 0; nt < 4; ++nt)
          acc[mt][nt] = __builtin_amdgcn_mfma_f32_16x16x32_bf16(
              Af[d][mt], Bf[d][nt], acc[mt][nt], 0, 0, 0);
#pragma unroll
      for (int mt = 0; mt < 4; ++mt)
        Af[d][mt] = *(const bf16x8*)(ap + d * 4096 + mt * 1024 + lane_off);
#pragma unroll
      for (int nt = 0; nt < 4; ++nt)
        Bf[d][nt] = *(const bf16x8*)(bp + d * 4096 + nt * 1024 + lane_off);
    }
  }
#pragma unroll
  for (int d = 0; d < D; ++d) {
#pragma unroll
    for (int mt = 0; mt < 4; ++mt)
#pragma unroll
      for (int nt = 0; nt < 4; ++nt)
        acc[mt][nt] = __builtin_amdgcn_mfma_f32_16x16x32_bf16(
            Af[d][mt], Bf[d][nt], acc[mt][nt], 0, 0, 0);
  }
}

// per-atom MLP (all 64 lanes of one wave; ins uniform across lanes)
__device__ __forceinline__ void mlp_core(const P& p, int b, int a, int lane,
                                         const float ins[4]) {
  int j = lane;
  float h1 = p.b1[j] + ins[0] * p.W1[j * 4 + 0] + ins[1] * p.W1[j * 4 + 1] +
             ins[2] * p.W1[j * 4 + 2] + ins[3] * p.W1[j * 4 + 3];
  h1 = fmaxf(h1, 0.f);
  float h2 = p.b2[j];
  const float4* w2r = (const float4*)(p.W2 + j * 64);
#pragma unroll
  for (int k4 = 0; k4 < 16; ++k4) {
    float4 wv = w2r[k4];
    h2 += __shfl(h1, k4 * 4 + 0) * wv.x + __shfl(h1, k4 * 4 + 1) * wv.y +
          __shfl(h1, k4 * 4 + 2) * wv.z + __shfl(h1, k4 * 4 + 3) * wv.w;
  }
  h2 = fmaxf(h2, 0.f);
  int mh = b >> 6, mloc = b & 63, mt = mloc >> 4, ln2 = mloc & 15;
  int ch = a * 2 + (j >> 5), quad2 = (j >> 3) & 3, jj = j & 7;
  size_t xi = ((size_t)(mh * 180 + ch) * 4 + mt) * 512 + (quad2 * 16 + ln2) * 8 + jj;
  p.A0[xi] = f2bf(h2);
}

// Gates GEMM + fused LSTM cell: block = (jb, mh); wave w = K-chunk w (30 iters);
// LDS reduce; wave w applies the cell to m-tile w. nt == gate (i,f,g,o).
__device__ __forceinline__ void gates_unit(const P& p, int layer, int jb, int mh,
                                           int w, int lane,
                                           float (&red)[4][4][16][64],
                                           int rd_off, int wr_off) {
  const int ln = lane & 15, quad = lane >> 4;
  const int lane_off = lane * 16;
  const u16* Atl = layer ? p.A1 : p.A0;
  const char* ax = (const char*)Atl + (size_t)mh * 180 * 4096;
  const char* ah = ax + (size_t)rd_off * 4096;
  const char* aw = (w < 2) ? (ax + (size_t)(30 * w) * 4096)
                           : (ah + (size_t)(30 * (w - 2)) * 4096);
  const char* bw = (const char*)(p.Brep + (size_t)layer * 120 * 120 * 2048) +
                   ((size_t)jb * 120 + 30 * w) * 4096;
  const float* bihl = p.bih + layer * 7680;
  const float* bhhl = p.bhh + layer * 7680;
  float* c_l = p.cbuf + layer * 245760;
  u16* hA = (layer ? p.A1 : p.A0) + (size_t)wr_off * 2048;
  u16* hB = layer ? p.A2 : p.A1;
  const int sB = layer ? 60 : 180;

  f32x4 acc[4][4] = {};
  gemm_pipe<30>(aw, bw, lane_off, acc);

#pragma unroll
  for (int mt = 0; mt < 4; ++mt)
#pragma unroll
    for (int nt = 0; nt < 4; ++nt)
      *(f32x4*)&red[w][nt][ln][mt * 16 + quad * 4] = acc[mt][nt];
  __syncthreads();

  f32x4 g[4];
#pragma unroll
  for (int nt = 0; nt < 4; ++nt) {
    f32x4 s = *(const f32x4*)&red[0][nt][ln][w * 16 + quad * 4];
#pragma unroll
    for (int pp = 1; pp < 4; ++pp) {
      f32x4 tv = *(const f32x4*)&red[pp][nt][ln][w * 16 + quad * 4];
      s[0] += tv[0]; s[1] += tv[1]; s[2] += tv[2]; s[3] += tv[3];
    }
    g[nt] = s;
  }

  const int kh = jb * 16 + ln;
  const int chl = kh >> 5, quad2 = (kh >> 3) & 3, jj = kh & 7;
  float bs[4];
#pragma unroll
  for (int gi = 0; gi < 4; ++gi) bs[gi] = bihl[gi * 1920 + kh] + bhhl[gi * 1920 + kh];
#pragma unroll
  for (int r = 0; r < 4; ++r) {
    int m = mh * 64 + w * 16 + quad * 4 + r;
    float vi = g[0][r] + bs[0];
    float vf = g[1][r] + bs[1];
    float vg = g[2][r] + bs[2];
    float vo = g[3][r] + bs[3];
    size_t ci = (size_t)m * 1920 + kh;
    float cn = sigm(vf) * c_l[ci] + sigm(vi) * tanhfast(vg);
    float hn = sigm(vo) * tanhfast(cn);
    c_l[ci] = cn;
    u16 hb = f2bf(hn);
    int lane2 = quad2 * 16 + quad * 4 + r;
    size_t hi = ((size_t)(mh * 180 + chl) * 4 + w) * 512 + lane2 * 8 + jj;
    hA[hi] = hb;
    size_t hi2 = ((size_t)(mh * sB + chl) * 4 + w) * 512 + lane2 * 8 + jj;
    hB[hi2] = hb;
  }
}

// W3 GEMM + relu -> plain bf16 [128,1920]. block = (nb, mh), 4-wave K-split.
__device__ __forceinline__ void w3_unit(const P& p, int nb, int mh, int w, int lane,
                                        float (&red)[4][4][16][64]) {
  const int ln = lane & 15, quad = lane >> 4;
  const int lane_off = lane * 16;
  const char* aw = (const char*)p.A2 + ((size_t)mh * 60 + 15 * w) * 4096;
  const char* bw = (const char*)p.W3r + ((size_t)nb * 60 + 15 * w) * 4096;

  f32x4 acc[4][4] = {};
  gemm_pipe<15>(aw, bw, lane_off, acc);

#pragma unroll
  for (int mt = 0; mt < 4; ++mt)
#pragma unroll
    for (int nt = 0; nt < 4; ++nt)
      *(f32x4*)&red[w][nt][ln][mt * 16 + quad * 4] = acc[mt][nt];
  __syncthreads();

#pragma unroll
  for (int nt = 0; nt < 4; ++nt) {
    f32x4 s = *(const f32x4*)&red[0][nt][ln][w * 16 + quad * 4];
#pragma unroll
    for (int pp = 1; pp < 4; ++pp) {
      f32x4 tv = *(const f32x4*)&red[pp][nt][ln][w * 16 + quad * 4];
      s[0] += tv[0]; s[1] += tv[1]; s[2] += tv[2]; s[3] += tv[3];
    }
    int n = nb * 64 + nt * 16 + ln;
    float bias = p.b3[n];
#pragma unroll
    for (int r = 0; r < 4; ++r) {
      int m = mh * 64 + w * 16 + quad * 4 + r;
      p.X3b[(size_t)m * 1920 + n] = f2bf(fmaxf(s[r] + bias, 0.f));
    }
  }
}

// W4 projection + bias + residual for unit (m,pb); then (fused) next-step MLP for
// atoms 2pb, 2pb+1 — ins values stay in registers across timesteps.
__device__ __forceinline__ void w4mlp_unit(const P& p, int m, int pb, int lane,
                                           int t, float* insreg, bool do_mlp,
                                           int burn) {
  const u16* xr = p.X3b + (size_t)m * 1920;
  float xv[30];
#pragma unroll
  for (int i = 0; i < 30; ++i) xv[i] = bf2f(xr[lane + 64 * i]);
  float vs[8];
#pragma unroll
  for (int pi = 0; pi < 8; ++pi) {
    int pp = pb * 8 + pi;
    const float* wr = p.W4 + (size_t)pp * 1920;
    float s = 0.f;
#pragma unroll
    for (int i = 0; i < 30; ++i) s += xv[i] * wr[lane + 64 * i];
#pragma unroll
    for (int off = 32; off > 0; off >>= 1) s += __shfl_xor(s, off);
    float v = s + p.b4[pp] + insreg[pi];
    vs[pi] = v;
    if (lane == 0)
      p.outp[(((size_t)m * 30 + (pp >> 2)) * 64 + t) * 4 + (pp & 3)] = v;
  }
  if (do_mlp) {
    bool gt = (t + 1) <= burn;
#pragma unroll
    for (int ai = 0; ai < 2; ++ai) {
      int a = pb * 2 + ai;
      int ba = m * 30 + a;
      float ins[4];
#pragma unroll
      for (int f = 0; f < 4; ++f)
        ins[f] = gt ? p.inputs[((size_t)ba * 65 + (t + 1)) * 4 + f] : vs[ai * 4 + f];
      mlp_core(p, m, a, lane, ins);
#pragma unroll
      for (int f = 0; f < 4; ++f) insreg[ai * 4 + f] = ins[f];
    }
  }
}

__global__ void __launch_bounds__(256, 1) k_persist(P p) {
  __shared__ float red[4][4][16][64];   // 64 KB
  const int bid = blockIdx.x;
  const int tid = threadIdx.x;
  const int w = tid >> 6, lane = tid & 63;
  const int burn = *p.burn;
  unsigned nbar = 0;

  // co-XCD decode: pair (jb,mh=0) and (jb,mh=1) are bids jb and jb+120
  // (120 % 8 == 0 -> same XCD -> one L2 fetch of the shared B slice)
  const int g_jb = bid % 120;
  const int g_mh = bid / 120;
  const bool w3_act = (g_jb < 30);

  // static unit assignment for w4+mlp: two (m,pb) units per wave
  int um[2], upb[2];
  float insreg[2][8];
#pragma unroll
  for (int u2 = 0; u2 < 2; ++u2) {
    int u = bid * 8 + w * 2 + u2;
    um[u2] = u / 15;
    upb[u2] = u - um[u2] * 15;
  }

  // t=0 MLP phase (ground-truth inputs; t=0 <= burn always)
#pragma unroll
  for (int u2 = 0; u2 < 2; ++u2) {
    int m = um[u2], pb = upb[u2];
#pragma unroll
    for (int ai = 0; ai < 2; ++ai) {
      int a = pb * 2 + ai, ba = m * 30 + a;
      float ins[4];
#pragma unroll
      for (int f = 0; f < 4; ++f)
        ins[f] = p.inputs[((size_t)ba * 65 + 0) * 4 + f];
      mlp_core(p, m, a, lane, ins);
#pragma unroll
      for (int f = 0; f < 4; ++f) insreg[u2][ai * 4 + f] = ins[f];
    }
  }
  nbar++; gbar(p.bar, nbar * NBLK);

  for (int t = 0; t < 64; ++t) {
    const int par = t & 1;
    const int rd_off = 60 + par * 60;
    const int wr_off = 60 + (1 - par) * 60;

    gates_unit(p, 0, g_jb, g_mh, w, lane, red, rd_off, wr_off);
    nbar++; gbar(p.bar, nbar * NBLK);
    gates_unit(p, 1, g_jb, g_mh, w, lane, red, rd_off, wr_off);
    nbar++; gbar(p.bar, nbar * NBLK);
    if (w3_act) w3_unit(p, g_jb, g_mh, w, lane, red);
    nbar++; gbar(p.bar, nbar * NBLK);
    const bool do_mlp = (t < 63);
#pragma unroll
    for (int u2 = 0; u2 < 2; ++u2)
      w4mlp_unit(p, um[u2], upb[u2], lane, t, insreg[u2], do_mlp, burn);
    if (t < 63) { nbar++; gbar(p.bar, nbar * NBLK); }
  }
}

extern "C" void kernel_launch(void* const* d_in, const int* in_sizes, int n_in,
                              void* d_out, int out_size, void* d_ws, size_t ws_size,
                              hipStream_t stream) {
  (void)in_sizes; (void)n_in; (void)out_size;
  const float* inputs = (const float*)d_in[0];
  const float* W1 = (const float*)d_in[1];
  const float* b1 = (const float*)d_in[2];
  const float* W2 = (const float*)d_in[3];
  const float* b2 = (const float*)d_in[4];
  const float* Wih = (const float*)d_in[5];
  const float* Whh = (const float*)d_in[6];
  const float* bih = (const float*)d_in[7];
  const float* bhh = (const float*)d_in[8];
  const float* W3 = (const float*)d_in[9];
  const float* b3 = (const float*)d_in[10];
  const float* W4 = (const float*)d_in[11];
  const float* b4 = (const float*)d_in[12];
  const int* burn = (const int*)d_in[14];
  float* outp = (float*)d_out;
  char* ws = (char*)d_ws;

  // ---- workspace layout (bytes) ----
  // zero region: c (1966080) + A0 (1474560) + A1 (1474560) + bar (256) = 4915456
  float* cbuf = (float*)ws;                          // [2][128][1920] f32
  u16* A0 = (u16*)(ws + 1966080);                    // [2mh][180ch][4][512] u16
  u16* A1 = (u16*)(ws + 3440640);
  unsigned* bar = (unsigned*)(ws + 4915200);         // barrier counter (zeroed)
  u16* A2 = (u16*)(ws + 4915456);                    // [2mh][60ch][4][512] u16
  u16* X3b = (u16*)(ws + 5406976);                   // [128][1920] bf16
  u16* Brep = (u16*)(ws + 5898496);                  // 58982400 u16
  u16* W3r = (u16*)(ws + 123863296);                 // 3686400 u16
  if (ws_size < 131236096) return;                   // insufficient scratch

  // zero c + A0 + A1 + bar (1228864 floats)
  hipLaunchKernelGGL(k_zero, dim3(4801), dim3(256), 0, stream, (float*)ws,
                     1228864);
  // repack weights to bf16 fragment-tiled
  hipLaunchKernelGGL(k_repB, dim3(28800), dim3(256), 0, stream, Wih, Whh, Brep);
  hipLaunchKernelGGL(k_repW3, dim3(1800), dim3(256), 0, stream, W3, W3r);

  P prm;
  prm.inputs = inputs;
  prm.W1 = W1; prm.b1 = b1; prm.W2 = W2; prm.b2 = b2;
  prm.bih = bih; prm.bhh = bhh;
  prm.b3 = b3; prm.W4 = W4; prm.b4 = b4;
  prm.burn = burn;
  prm.outp = outp;
  prm.cbuf = cbuf;
  prm.A0 = A0; prm.A1 = A1; prm.A2 = A2; prm.X3b = X3b;
  prm.Brep = Brep; prm.W3r = W3r;
  prm.bar = bar;

  hipLaunchKernelGGL(k_persist, dim3(NBLK), dim3(256), 0, stream, prm);
}